// Round 1
// baseline (480.908 us; speedup 1.0000x reference)
//
#include <hip/hip_runtime.h>

#define BB 4
#define TT 2048
#define CC 1024
#define HH 16
#define DD 64

typedef unsigned short u16;
typedef __bf16 bf16;
typedef __attribute__((ext_vector_type(8))) bf16 bf16x8;
typedef __attribute__((ext_vector_type(8))) u16 u16x8;
typedef __attribute__((ext_vector_type(4))) float f32x4;

static __device__ __forceinline__ u16 f2b(float f) {
  unsigned u = __builtin_bit_cast(unsigned, f);
  u += 0x7fffu + ((u >> 16) & 1u);
  return (u16)(u >> 16);
}

// ---------------- fp32 -> bf16 bulk convert (8 elems/thread) ----------------
__global__ void cvt_bf16_kernel(const float* __restrict__ src, u16* __restrict__ dst, int n8) {
  int i = blockIdx.x * blockDim.x + threadIdx.x;
  if (i >= n8) return;
  const float4* p4 = reinterpret_cast<const float4*>(src) + (size_t)i * 2;
  float4 a = p4[0], b = p4[1];
  u16x8 o;
  o[0] = f2b(a.x); o[1] = f2b(a.y); o[2] = f2b(a.z); o[3] = f2b(a.w);
  o[4] = f2b(b.x); o[5] = f2b(b.y); o[6] = f2b(b.z); o[7] = f2b(b.w);
  *reinterpret_cast<u16x8*>(dst + (size_t)i * 8) = o;
}

// ------------- W[k][n] fp32  ->  Wt[n][k] bf16  (32x32 LDS tile) -------------
__global__ void transp_w_kernel(const float* __restrict__ w0, const float* __restrict__ w1,
                                const float* __restrict__ w2, const float* __restrict__ w3,
                                u16* __restrict__ wqkvT, u16* __restrict__ wpT) {
  __shared__ float t[32][33];
  int z = blockIdx.z;
  const float* src = z == 0 ? w0 : z == 1 ? w1 : z == 2 ? w2 : w3;
  u16* dst = z < 3 ? wqkvT + (size_t)z * CC * CC : wpT;
  int k0 = blockIdx.x * 32, n0 = blockIdx.y * 32;
  int tx = threadIdx.x & 31, ty = threadIdx.x >> 5;
#pragma unroll
  for (int i = 0; i < 4; ++i)
    t[ty + i * 8][tx] = src[(size_t)(k0 + ty + i * 8) * CC + n0 + tx];
  __syncthreads();
#pragma unroll
  for (int i = 0; i < 4; ++i)
    dst[(size_t)(n0 + ty + i * 8) * CC + k0 + tx] = f2b(t[tx][ty + i * 8]);
}

// ---------------- bf16 GEMM: C[m][n] = sum_k A[m][k]*Bt[n][k] ----------------
// 128x128 tile, BK=32, 4 waves (each 64x64), 16x16x32 MFMA, global_load_lds.
// MODE 0: QKV epilogue -> scatter bf16 to [B,H,T,D] x3 with bias
// MODE 1: fp32 out[m*N+n] = acc + bias[n]
template <int MODE>
__global__ __launch_bounds__(256) void gemm_bt_kernel(
    const u16* __restrict__ A, const u16* __restrict__ Bt, int K, int N,
    const float* __restrict__ b0, const float* __restrict__ b1, const float* __restrict__ b2,
    u16* __restrict__ q_out, u16* __restrict__ k_out, u16* __restrict__ v_out,
    float* __restrict__ f_out) {
  __shared__ u16 As[128 * 32];
  __shared__ u16 Bs[128 * 32];
  const int tid = threadIdx.x, lane = tid & 63, w = tid >> 6;
  const int wm = w >> 1, wn = w & 1;
  const int m0 = blockIdx.x * 128, n0 = blockIdx.y * 128;
  const int lrow = lane >> 2, lcol = (lane & 3) * 8;
  f32x4 acc[4][4] = {};

  for (int k0 = 0; k0 < K; k0 += 32) {
    if (k0) __syncthreads();
#pragma unroll
    for (int r = 0; r < 2; ++r) {
      int row = r * 64 + w * 16 + lrow;
      __builtin_amdgcn_global_load_lds(
          (const __attribute__((address_space(1))) void*)(A + (size_t)(m0 + row) * K + k0 + lcol),
          (__attribute__((address_space(3))) void*)(As + (r * 64 + w * 16) * 32),
          16, 0, 0);
      __builtin_amdgcn_global_load_lds(
          (const __attribute__((address_space(1))) void*)(Bt + (size_t)(n0 + row) * K + k0 + lcol),
          (__attribute__((address_space(3))) void*)(Bs + (r * 64 + w * 16) * 32),
          16, 0, 0);
    }
    __syncthreads();
    bf16x8 af[4], bfr[4];
#pragma unroll
    for (int i = 0; i < 4; ++i) {
      af[i] = *reinterpret_cast<const bf16x8*>(&As[(wm * 64 + i * 16 + (lane & 15)) * 32 + (lane >> 4) * 8]);
      bfr[i] = *reinterpret_cast<const bf16x8*>(&Bs[(wn * 64 + i * 16 + (lane & 15)) * 32 + (lane >> 4) * 8]);
    }
#pragma unroll
    for (int i = 0; i < 4; ++i)
#pragma unroll
      for (int j = 0; j < 4; ++j)
        acc[i][j] = __builtin_amdgcn_mfma_f32_16x16x32_bf16(af[i], bfr[j], acc[i][j], 0, 0, 0);
  }

  const int mrow = m0 + wm * 64;
  const int ncol = n0 + wn * 64;
  if (MODE == 0) {
    const int g = n0 >> 10;  // uniform per block (128 | 1024)
    const float* bias = g == 0 ? b0 : g == 1 ? b1 : b2;
    u16* dst = g == 0 ? q_out : g == 1 ? k_out : v_out;
#pragma unroll
    for (int i = 0; i < 4; ++i)
#pragma unroll
      for (int j = 0; j < 4; ++j)
#pragma unroll
        for (int r = 0; r < 4; ++r) {
          int m = mrow + i * 16 + (lane >> 4) * 4 + r;
          int n = ncol + j * 16 + (lane & 15);
          float v = acc[i][j][r] + bias[n & 1023];
          int b = m >> 11, t = m & 2047;
          int h = (n >> 6) & 15, d = n & 63;
          dst[(((size_t)(b * HH + h)) * TT + t) * DD + d] = f2b(v);
        }
  } else {
#pragma unroll
    for (int i = 0; i < 4; ++i)
#pragma unroll
      for (int j = 0; j < 4; ++j)
#pragma unroll
        for (int r = 0; r < 4; ++r) {
          int m = mrow + i * 16 + (lane >> 4) * 4 + r;
          int n = ncol + j * 16 + (lane & 15);
          f_out[(size_t)m * N + n] = acc[i][j][r] + b0[n];
        }
  }
}

// ---------------- causal flash attention, bf16 QKV in [B,H,T,D] ----------------
// block: 4 waves, 128 q-rows (32/wave). KV tiles of 32.
__global__ __launch_bounds__(256) void attn_kernel(
    const u16* __restrict__ Q, const u16* __restrict__ K, const u16* __restrict__ V,
    const int* __restrict__ am, u16* __restrict__ Y) {
  __shared__ u16 Ks[32 * 72];      // K tile [kv][d], stride 72 (bank spread, 16B aligned)
  __shared__ u16 Vt[64 * 40];      // V^T tile [d][kv], stride 40
  __shared__ u16 Pls[4][32 * 40];  // per-wave P buffer [q][kv], stride 40
  const int tid = threadIdx.x, lane = tid & 63, w = tid >> 6;
  const int qb = blockIdx.x, bh = blockIdx.y;
  const int b = bh >> 4, h = bh & 15;
  const int q0 = qb * 128 + w * 32;
  const u16* Qb = Q + (size_t)bh * TT * DD;
  const u16* Kb = K + (size_t)bh * TT * DD;
  const u16* Vb = V + (size_t)bh * TT * DD;

  bf16x8 qf[2][2];
#pragma unroll
  for (int mf = 0; mf < 2; ++mf)
#pragma unroll
    for (int ks = 0; ks < 2; ++ks)
      qf[mf][ks] = *reinterpret_cast<const bf16x8*>(
          Qb + (size_t)(q0 + mf * 16 + (lane & 15)) * DD + ks * 32 + (lane >> 4) * 8);

  f32x4 o[2][4] = {};
  float mrun[2][4], lrun[2][4];
#pragma unroll
  for (int i = 0; i < 2; ++i)
#pragma unroll
    for (int r = 0; r < 4; ++r) { mrun[i][r] = -1e30f; lrun[i][r] = 0.f; }

  const int nkt = (qb + 1) * 4;
  const int srow = tid >> 3, scol = (tid & 7) * 8;
  for (int kt = 0; kt < nkt; ++kt) {
    const int kv0 = kt * 32;
    __syncthreads();
    u16x8 kv8 = *reinterpret_cast<const u16x8*>(Kb + (size_t)(kv0 + srow) * DD + scol);
    *reinterpret_cast<u16x8*>(&Ks[srow * 72 + scol]) = kv8;
    u16x8 vv8 = *reinterpret_cast<const u16x8*>(Vb + (size_t)(kv0 + srow) * DD + scol);
#pragma unroll
    for (int j = 0; j < 8; ++j) Vt[(scol + j) * 40 + srow] = vv8[j];
    __syncthreads();

    // S = Q K^T
    f32x4 s[2][2] = {};
#pragma unroll
    for (int nf = 0; nf < 2; ++nf)
#pragma unroll
      for (int ks = 0; ks < 2; ++ks) {
        bf16x8 kf = *reinterpret_cast<const bf16x8*>(
            &Ks[(nf * 16 + (lane & 15)) * 72 + ks * 32 + (lane >> 4) * 8]);
#pragma unroll
        for (int mf = 0; mf < 2; ++mf)
          s[mf][nf] = __builtin_amdgcn_mfma_f32_16x16x32_bf16(qf[mf][ks], kf, s[mf][nf], 0, 0, 0);
      }

    // scale + causal + key mask
    int km[2];
#pragma unroll
    for (int nf = 0; nf < 2; ++nf) km[nf] = am[b * TT + kv0 + nf * 16 + (lane & 15)];
#pragma unroll
    for (int mf = 0; mf < 2; ++mf)
#pragma unroll
      for (int nf = 0; nf < 2; ++nf) {
        int kv = kv0 + nf * 16 + (lane & 15);
#pragma unroll
        for (int r = 0; r < 4; ++r) {
          int q = q0 + mf * 16 + (lane >> 4) * 4 + r;
          float v = s[mf][nf][r] * 0.125f;
          s[mf][nf][r] = (kv <= q && km[nf] != 0) ? v : -1e30f;
        }
      }

    // online softmax (wave-parallel row reduce over 16-lane col groups)
#pragma unroll
    for (int mf = 0; mf < 2; ++mf)
#pragma unroll
      for (int r = 0; r < 4; ++r) {
        float rm = fmaxf(s[mf][0][r], s[mf][1][r]);
#pragma unroll
        for (int x = 1; x < 16; x <<= 1) rm = fmaxf(rm, __shfl_xor(rm, x, 64));
        float mnew = fmaxf(mrun[mf][r], rm);
        float corr = __expf(mrun[mf][r] - mnew);
        float p0 = __expf(s[mf][0][r] - mnew);
        float p1 = __expf(s[mf][1][r] - mnew);
        float rs = p0 + p1;
#pragma unroll
        for (int x = 1; x < 16; x <<= 1) rs += __shfl_xor(rs, x, 64);
        lrun[mf][r] = lrun[mf][r] * corr + rs;
        mrun[mf][r] = mnew;
#pragma unroll
        for (int nd = 0; nd < 4; ++nd) o[mf][nd][r] *= corr;
        int prow = mf * 16 + (lane >> 4) * 4 + r;
        Pls[w][prow * 40 + (lane & 15)] = f2b(p0);
        Pls[w][prow * 40 + 16 + (lane & 15)] = f2b(p1);
      }

    // O += P V  (P via per-wave LDS relayout; same-wave LDS ops are in-order)
#pragma unroll
    for (int mf = 0; mf < 2; ++mf) {
      bf16x8 pa = *reinterpret_cast<const bf16x8*>(
          &Pls[w][(mf * 16 + (lane & 15)) * 40 + (lane >> 4) * 8]);
#pragma unroll
      for (int nd = 0; nd < 4; ++nd) {
        bf16x8 vf = *reinterpret_cast<const bf16x8*>(
            &Vt[(nd * 16 + (lane & 15)) * 40 + (lane >> 4) * 8]);
        o[mf][nd] = __builtin_amdgcn_mfma_f32_16x16x32_bf16(pa, vf, o[mf][nd], 0, 0, 0);
      }
    }
  }

  // epilogue: Y[b][t][h*64+d] (bf16, [B,T,C] layout for the proj GEMM)
#pragma unroll
  for (int mf = 0; mf < 2; ++mf)
#pragma unroll
    for (int nd = 0; nd < 4; ++nd)
#pragma unroll
      for (int r = 0; r < 4; ++r) {
        int q = q0 + mf * 16 + (lane >> 4) * 4 + r;
        int d = nd * 16 + (lane & 15);
        float v = o[mf][nd][r] / lrun[mf][r];
        Y[((size_t)(b * TT + q)) * CC + h * DD + d] = f2b(v);
      }
}

extern "C" void kernel_launch(void* const* d_in, const int* in_sizes, int n_in,
                              void* d_out, int out_size, void* d_ws, size_t ws_size,
                              hipStream_t stream) {
  const float* x  = (const float*)d_in[0];
  const int*   am = (const int*)d_in[1];
  const float* Wq = (const float*)d_in[2];
  const float* bq = (const float*)d_in[3];
  const float* Wk = (const float*)d_in[4];
  const float* bk = (const float*)d_in[5];
  const float* Wv = (const float*)d_in[6];
  const float* bv = (const float*)d_in[7];
  const float* Wp = (const float*)d_in[8];
  const float* bp = (const float*)d_in[9];
  float* out = (float*)d_out;

  char* ws = (char*)d_ws;
  u16* xb    = (u16*)(ws);                        // 16 MB  [8192][1024] bf16
  u16* wqkvT = (u16*)(ws + (16ull << 20));        //  6 MB  [3072][1024] bf16 (W^T)
  u16* wpT   = (u16*)(ws + (22ull << 20));        //  2 MB  [1024][1024] bf16 (Wp^T)
  u16* qw    = (u16*)(ws + (24ull << 20));        // 16 MB  [B,H,T,D] bf16
  u16* kw    = (u16*)(ws + (40ull << 20));        // 16 MB
  u16* vw    = (u16*)(ws + (56ull << 20));        // 16 MB
  u16* yb    = (u16*)(ws + (72ull << 20));        // 16 MB  [B,T,C] bf16

  // 1. convert x to bf16
  {
    int n8 = BB * TT * CC / 8;
    cvt_bf16_kernel<<<n8 / 256, 256, 0, stream>>>(x, xb, n8);
  }
  // 2. transpose-convert weights
  transp_w_kernel<<<dim3(32, 32, 4), 256, 0, stream>>>(Wq, Wk, Wv, Wp, wqkvT, wpT);
  // 3. QKV projection GEMM: [8192,1024] x [1024,3072]
  gemm_bt_kernel<0><<<dim3(64, 24), 256, 0, stream>>>(
      xb, wqkvT, CC, 3 * CC, bq, bk, bv, qw, kw, vw, nullptr);
  // 4. causal flash attention
  attn_kernel<<<dim3(16, 64), 256, 0, stream>>>(qw, kw, vw, am, yb);
  // 5. output projection GEMM: [8192,1024] x [1024,1024] -> fp32 out
  gemm_bt_kernel<1><<<dim3(64, 8), 256, 0, stream>>>(
      yb, wpT, CC, CC, bp, nullptr, nullptr, nullptr, nullptr, nullptr, out);
}

// Round 2
// 245.469 us; speedup vs baseline: 1.9591x; 1.9591x over previous
//
#include <hip/hip_runtime.h>

#define BB 4
#define TT 2048
#define CC 1024
#define HH 16
#define DD 64

typedef unsigned short u16;
typedef unsigned int u32;
typedef __bf16 bf16;
typedef __attribute__((ext_vector_type(8))) bf16 bf16x8;
typedef __attribute__((ext_vector_type(8))) u16 u16x8;
typedef __attribute__((ext_vector_type(4))) u16 u16x4;
typedef __attribute__((ext_vector_type(4))) float f32x4;

static __device__ __forceinline__ u16 f2b(float f) {
  unsigned u = __builtin_bit_cast(unsigned, f);
  u += 0x7fffu + ((u >> 16) & 1u);
  return (u16)(u >> 16);
}
static __device__ __forceinline__ u16 bfc(float f) {
  return __builtin_bit_cast(u16, (__bf16)f);
}
static __device__ __forceinline__ u32 pkbf(float a, float b) {
  return (u32)bfc(a) | ((u32)bfc(b) << 16);
}

// ---------------- fp32 -> bf16 bulk convert (8 elems/thread) ----------------
__global__ void cvt_bf16_kernel(const float* __restrict__ src, u16* __restrict__ dst, int n8) {
  int i = blockIdx.x * blockDim.x + threadIdx.x;
  if (i >= n8) return;
  const float4* p4 = reinterpret_cast<const float4*>(src) + (size_t)i * 2;
  float4 a = p4[0], b = p4[1];
  u16x8 o;
  o[0] = f2b(a.x); o[1] = f2b(a.y); o[2] = f2b(a.z); o[3] = f2b(a.w);
  o[4] = f2b(b.x); o[5] = f2b(b.y); o[6] = f2b(b.z); o[7] = f2b(b.w);
  *reinterpret_cast<u16x8*>(dst + (size_t)i * 8) = o;
}

// ------------- W[k][n] fp32  ->  Wt[n][k] bf16  (32x32 LDS tile) -------------
__global__ void transp_w_kernel(const float* __restrict__ w0, const float* __restrict__ w1,
                                const float* __restrict__ w2, const float* __restrict__ w3,
                                u16* __restrict__ wqkvT, u16* __restrict__ wpT) {
  __shared__ float t[32][33];
  int z = blockIdx.z;
  const float* src = z == 0 ? w0 : z == 1 ? w1 : z == 2 ? w2 : w3;
  u16* dst = z < 3 ? wqkvT + (size_t)z * CC * CC : wpT;
  int k0 = blockIdx.x * 32, n0 = blockIdx.y * 32;
  int tx = threadIdx.x & 31, ty = threadIdx.x >> 5;
#pragma unroll
  for (int i = 0; i < 4; ++i)
    t[ty + i * 8][tx] = src[(size_t)(k0 + ty + i * 8) * CC + n0 + tx];
  __syncthreads();
#pragma unroll
  for (int i = 0; i < 4; ++i)
    dst[(size_t)(n0 + ty + i * 8) * CC + k0 + tx] = f2b(t[tx][ty + i * 8]);
}

// ---------------- bf16 GEMM: C[m][n] = sum_k A[m][k]*Bt[n][k] ----------------
// MODE 0: QKV epilogue -> Q,K scatter to [B,H,T,D]; V to [B,H,D,T] (transposed)
// MODE 1: fp32 out[m*N+n] = acc + bias[n]
template <int MODE>
__global__ __launch_bounds__(256) void gemm_bt_kernel(
    const u16* __restrict__ A, const u16* __restrict__ Bt, int K, int N,
    const float* __restrict__ b0, const float* __restrict__ b1, const float* __restrict__ b2,
    u16* __restrict__ q_out, u16* __restrict__ k_out, u16* __restrict__ v_out,
    float* __restrict__ f_out) {
  __shared__ u16 As[128 * 32];
  __shared__ u16 Bs[128 * 32];
  const int tid = threadIdx.x, lane = tid & 63, w = tid >> 6;
  const int wm = w >> 1, wn = w & 1;
  const int m0 = blockIdx.x * 128, n0 = blockIdx.y * 128;
  const int lrow = lane >> 2, lcol = (lane & 3) * 8;
  f32x4 acc[4][4] = {};

  for (int k0 = 0; k0 < K; k0 += 32) {
    if (k0) __syncthreads();
#pragma unroll
    for (int r = 0; r < 2; ++r) {
      int row = r * 64 + w * 16 + lrow;
      __builtin_amdgcn_global_load_lds(
          (const __attribute__((address_space(1))) void*)(A + (size_t)(m0 + row) * K + k0 + lcol),
          (__attribute__((address_space(3))) void*)(As + (r * 64 + w * 16) * 32),
          16, 0, 0);
      __builtin_amdgcn_global_load_lds(
          (const __attribute__((address_space(1))) void*)(Bt + (size_t)(n0 + row) * K + k0 + lcol),
          (__attribute__((address_space(3))) void*)(Bs + (r * 64 + w * 16) * 32),
          16, 0, 0);
    }
    __syncthreads();
    bf16x8 af[4], bfr[4];
#pragma unroll
    for (int i = 0; i < 4; ++i) {
      af[i] = *reinterpret_cast<const bf16x8*>(&As[(wm * 64 + i * 16 + (lane & 15)) * 32 + (lane >> 4) * 8]);
      bfr[i] = *reinterpret_cast<const bf16x8*>(&Bs[(wn * 64 + i * 16 + (lane & 15)) * 32 + (lane >> 4) * 8]);
    }
#pragma unroll
    for (int i = 0; i < 4; ++i)
#pragma unroll
      for (int j = 0; j < 4; ++j)
        acc[i][j] = __builtin_amdgcn_mfma_f32_16x16x32_bf16(af[i], bfr[j], acc[i][j], 0, 0, 0);
  }

  const int mrow = m0 + wm * 64;
  const int ncol = n0 + wn * 64;
  if (MODE == 0) {
    const int g = n0 >> 10;  // 0:Q 1:K 2:V (uniform per block)
    const float* bias = g == 0 ? b0 : g == 1 ? b1 : b2;
    if (g < 2) {
      u16* dst = g == 0 ? q_out : k_out;
#pragma unroll
      for (int i = 0; i < 4; ++i)
#pragma unroll
        for (int j = 0; j < 4; ++j)
#pragma unroll
          for (int r = 0; r < 4; ++r) {
            int m = mrow + i * 16 + (lane >> 4) * 4 + r;
            int n = ncol + j * 16 + (lane & 15);
            float v = acc[i][j][r] + bias[n & 1023];
            int b = m >> 11, t = m & 2047;
            int h = (n >> 6) & 15, d = n & 63;
            dst[(((size_t)(b * HH + h)) * TT + t) * DD + d] = f2b(v);
          }
    } else {
      // V transposed: [B,H,D,T]; 4 consecutive t per lane -> 8B store
#pragma unroll
      for (int i = 0; i < 4; ++i)
#pragma unroll
        for (int j = 0; j < 4; ++j) {
          int n = ncol + j * 16 + (lane & 15);
          int h = (n >> 6) & 15, d = n & 63;
          float bias_v = bias[n & 1023];
          int mb = mrow + i * 16 + (lane >> 4) * 4;
          int b = mb >> 11, t = mb & 2047;
          u16x4 vv;
#pragma unroll
          for (int r = 0; r < 4; ++r) vv[r] = f2b(acc[i][j][r] + bias_v);
          *reinterpret_cast<u16x4*>(v_out + (((size_t)(b * HH + h)) * DD + d) * TT + t) = vv;
        }
    }
  } else {
#pragma unroll
    for (int i = 0; i < 4; ++i)
#pragma unroll
      for (int j = 0; j < 4; ++j)
#pragma unroll
        for (int r = 0; r < 4; ++r) {
          int m = mrow + i * 16 + (lane >> 4) * 4 + r;
          int n = ncol + j * 16 + (lane & 15);
          f_out[(size_t)m * N + n] = acc[i][j][r] + b0[n];
        }
  }
}

// ------------- causal flash attention, swapped operands, no KV staging -------------
// S^T = mfma(K,Q): lane owns q-cols -> in-lane softmax (+2 shuffles).
// O^T = mfma(V^T, P^T): corr/l stay lane-local. V pre-transposed [B,H,D,T].
// Each wave: 32 q-rows, processes complementary q-tiles (i, 63-i) -> equal work.
__global__ __launch_bounds__(256, 2) void attn_kernel(
    const u16* __restrict__ Q, const u16* __restrict__ K, const u16* __restrict__ Vt,
    const int* __restrict__ am, u16* __restrict__ Y) {
  __shared__ float maskf[TT];
  __shared__ u16 Pls[4][32 * 72];  // per-wave P buffer [32 q][64 kv], stride 72
  const int flat = blockIdx.x;
  const int work = (flat & 7) * 64 + (flat >> 3);  // XCD-chunked: 8 heads per XCD
  const int bh = work >> 3;
  const int x8 = work & 7;
  const int b = bh >> 4, h = bh & 15;

  for (int i = threadIdx.x; i < TT; i += 256)
    maskf[i] = am[b * TT + i] ? 0.f : -1e30f;
  __syncthreads();

  const int lane = threadIdx.x & 63, w = threadIdx.x >> 6;
  const int lq = lane & 15, g = lane >> 4;
  const int iw = x8 * 4 + w;  // 0..31 wave slot within head
  const u16* Qb = Q + (size_t)bh * TT * DD;
  const u16* Kb = K + (size_t)bh * TT * DD;
  const u16* Vb = Vt + (size_t)bh * DD * TT;
  u16* Pw = &Pls[w][0];

  for (int phase = 0; phase < 2; ++phase) {
    const int qt = phase == 0 ? iw : 63 - iw;
    const int q0 = qt * 32;

    bf16x8 qf[2][2];
#pragma unroll
    for (int n = 0; n < 2; ++n)
#pragma unroll
      for (int ks = 0; ks < 2; ++ks)
        qf[n][ks] = *reinterpret_cast<const bf16x8*>(
            Qb + (size_t)(q0 + n * 16 + lq) * DD + ks * 32 + g * 8);

    f32x4 o[4][2] = {};  // O^T: row d = nd*16+4g+r, col q = n*16+lq
    float mrun[2] = {-1e30f, -1e30f}, lrun[2] = {0.f, 0.f};

    const int nkt = (q0 >> 6) + 1;
    for (int kt = 0; kt < nkt; ++kt) {
      const int kv0 = kt * 64;
      // K fragments (A-operand), contiguous 16B from [T][D]
      bf16x8 kf[4][2];
#pragma unroll
      for (int m = 0; m < 4; ++m)
#pragma unroll
        for (int ks = 0; ks < 2; ++ks)
          kf[m][ks] = *reinterpret_cast<const bf16x8*>(
              Kb + (size_t)(kv0 + m * 16 + lq) * DD + ks * 32 + g * 8);

      // S^T[kv][q]
      f32x4 s[4][2] = {};
#pragma unroll
      for (int m = 0; m < 4; ++m)
#pragma unroll
        for (int ks = 0; ks < 2; ++ks)
#pragma unroll
          for (int n = 0; n < 2; ++n)
            s[m][n] = __builtin_amdgcn_mfma_f32_16x16x32_bf16(kf[m][ks], qf[n][ks], s[m][n], 0, 0, 0);

      // V^T fragments (A-operand for PV), issued early to hide latency under softmax
      bf16x8 vf[2][4];
#pragma unroll
      for (int ks = 0; ks < 2; ++ks)
#pragma unroll
        for (int nd = 0; nd < 4; ++nd)
          vf[ks][nd] = *reinterpret_cast<const bf16x8*>(
              Vb + (size_t)(nd * 16 + lq) * TT + kv0 + ks * 32 + g * 8);

      // scale + key-mask + causal
      float mv[4][4];
#pragma unroll
      for (int m = 0; m < 4; ++m)
#pragma unroll
        for (int r = 0; r < 4; ++r)
          mv[m][r] = maskf[kv0 + m * 16 + g * 4 + r];
#pragma unroll
      for (int n = 0; n < 2; ++n) {
        const int q = q0 + n * 16 + lq;
#pragma unroll
        for (int m = 0; m < 4; ++m)
#pragma unroll
          for (int r = 0; r < 4; ++r) {
            int kv = kv0 + m * 16 + g * 4 + r;
            float v = s[m][n][r] * 0.125f + mv[m][r];
            s[m][n][r] = (kv <= q) ? v : -1e30f;
          }
      }

      // online softmax per q-col (in-lane over 16 vals + 2 shuffles), P -> LDS
#pragma unroll
      for (int n = 0; n < 2; ++n) {
        float rm = -1e30f;
#pragma unroll
        for (int m = 0; m < 4; ++m)
#pragma unroll
          for (int r = 0; r < 4; ++r) rm = fmaxf(rm, s[m][n][r]);
        rm = fmaxf(rm, __shfl_xor(rm, 16));
        rm = fmaxf(rm, __shfl_xor(rm, 32));
        float mnew = fmaxf(mrun[n], rm);
        float corr = __expf(mrun[n] - mnew);
        mrun[n] = mnew;
        float rs = 0.f;
#pragma unroll
        for (int m = 0; m < 4; ++m) {
          float p0 = __expf(s[m][n][0] - mnew);
          float p1 = __expf(s[m][n][1] - mnew);
          float p2 = __expf(s[m][n][2] - mnew);
          float p3 = __expf(s[m][n][3] - mnew);
          rs += (p0 + p1) + (p2 + p3);
          uint2 pw;
          pw.x = pkbf(p0, p1);
          pw.y = pkbf(p2, p3);
          *reinterpret_cast<uint2*>(Pw + (n * 16 + lq) * 72 + m * 16 + g * 4) = pw;
        }
        rs += __shfl_xor(rs, 16);
        rs += __shfl_xor(rs, 32);
        lrun[n] = lrun[n] * corr + rs;
#pragma unroll
        for (int nd = 0; nd < 4; ++nd)
#pragma unroll
          for (int r = 0; r < 4; ++r) o[nd][n][r] *= corr;
      }

      asm volatile("s_waitcnt lgkmcnt(0)" ::: "memory");  // P visible wave-wide

      // O^T += V^T * P^T
#pragma unroll
      for (int ks = 0; ks < 2; ++ks) {
        bf16x8 pf[2];
#pragma unroll
        for (int n = 0; n < 2; ++n)
          pf[n] = *reinterpret_cast<const bf16x8*>(Pw + (n * 16 + lq) * 72 + ks * 32 + g * 8);
#pragma unroll
        for (int nd = 0; nd < 4; ++nd) {
          o[nd][0] = __builtin_amdgcn_mfma_f32_16x16x32_bf16(vf[ks][nd], pf[0], o[nd][0], 0, 0, 0);
          o[nd][1] = __builtin_amdgcn_mfma_f32_16x16x32_bf16(vf[ks][nd], pf[1], o[nd][1], 0, 0, 0);
        }
      }
    }

    // epilogue: Y[b][t][h*64+d] bf16
#pragma unroll
    for (int n = 0; n < 2; ++n) {
      float inv = 1.0f / lrun[n];
      const int q = q0 + n * 16 + lq;
#pragma unroll
      for (int nd = 0; nd < 4; ++nd)
#pragma unroll
        for (int r = 0; r < 4; ++r) {
          int d = nd * 16 + g * 4 + r;
          Y[((size_t)(b * TT + q)) * CC + h * DD + d] = bfc(o[nd][n][r] * inv);
        }
    }
  }
}

extern "C" void kernel_launch(void* const* d_in, const int* in_sizes, int n_in,
                              void* d_out, int out_size, void* d_ws, size_t ws_size,
                              hipStream_t stream) {
  const float* x  = (const float*)d_in[0];
  const int*   am = (const int*)d_in[1];
  const float* Wq = (const float*)d_in[2];
  const float* bq = (const float*)d_in[3];
  const float* Wk = (const float*)d_in[4];
  const float* bk = (const float*)d_in[5];
  const float* Wv = (const float*)d_in[6];
  const float* bv = (const float*)d_in[7];
  const float* Wp = (const float*)d_in[8];
  const float* bp = (const float*)d_in[9];
  float* out = (float*)d_out;

  char* ws = (char*)d_ws;
  u16* xb    = (u16*)(ws);                        // 16 MB  [8192][1024] bf16
  u16* wqkvT = (u16*)(ws + (16ull << 20));        //  6 MB  [3072][1024] bf16 (W^T)
  u16* wpT   = (u16*)(ws + (22ull << 20));        //  2 MB  [1024][1024] bf16 (Wp^T)
  u16* qw    = (u16*)(ws + (24ull << 20));        // 16 MB  [B,H,T,D] bf16
  u16* kw    = (u16*)(ws + (40ull << 20));        // 16 MB  [B,H,T,D] bf16
  u16* vw    = (u16*)(ws + (56ull << 20));        // 16 MB  [B,H,D,T] bf16 (transposed!)
  u16* yb    = (u16*)(ws + (72ull << 20));        // 16 MB  [B,T,C] bf16

  {
    int n8 = BB * TT * CC / 8;
    cvt_bf16_kernel<<<n8 / 256, 256, 0, stream>>>(x, xb, n8);
  }
  transp_w_kernel<<<dim3(32, 32, 4), 256, 0, stream>>>(Wq, Wk, Wv, Wp, wqkvT, wpT);
  gemm_bt_kernel<0><<<dim3(64, 24), 256, 0, stream>>>(
      xb, wqkvT, CC, 3 * CC, bq, bk, bv, qw, kw, vw, nullptr);
  attn_kernel<<<dim3(512), 256, 0, stream>>>(qw, kw, vw, am, yb);
  gemm_bt_kernel<1><<<dim3(64, 8), 256, 0, stream>>>(
      yb, wpT, CC, CC, bp, nullptr, nullptr, nullptr, nullptr, nullptr, out);
}